// Round 8
// baseline (991.766 us; speedup 1.0000x reference)
//
#include <hip/hip_runtime.h>
#include <hip/hip_bf16.h>
#include <math.h>

constexpr int NN = 60000;   // nodes
constexpr int NE = 480000;  // edges
constexpr int NB = 128;     // graphs
constexpr int NSB = (NN + 255) / 256;   // scan blocks = 235

typedef __attribute__((ext_vector_type(8))) short  short8;
typedef __attribute__((ext_vector_type(8))) unsigned short ushort8;
typedef __attribute__((ext_vector_type(4))) float  f32x4;

__device__ __forceinline__ unsigned short f2b(float x) {
    __hip_bfloat16 h = __float2bfloat16(x);   // RNE
    return *reinterpret_cast<unsigned short*>(&h);
}
__device__ __forceinline__ float b2f(unsigned short v) {
    return __uint_as_float((unsigned)v << 16);
}
// swizzled byte offset into a [64][512B] LDS tile: XOR 16B-chunk with row&7 (T2, G4)
__device__ __forceinline__ int swz(int row, int byte_in_row) {
    return row * 512 + (byte_in_row ^ ((row & 7) << 4));
}

// ---------------- edge features (bf16) + forward-in-time compaction + deg histogram ----------------
__global__ __launch_bounds__(256) void edge_compact_k(
    const float* __restrict__ x, const int* __restrict__ send, const int* __restrict__ recv,
    unsigned short* __restrict__ e8u, int* __restrict__ cse, int* __restrict__ cre,
    int* __restrict__ ecnt, int* __restrict__ deg)
{
    int e = blockIdx.x * 256 + threadIdx.x;
    if (e >= NE) return;
    int s = send[e], r = recv[e];
    const float* xs = x + (size_t)s * 6;
    const float* xr = x + (size_t)r * 6;
    float xs3 = xs[3], xr3 = xr[3];
    if (!(xs3 <= xr3)) return;                 // masked edge contributes nothing anywhere
    float d0 = xr[0] - xs[0], d1 = xr[1] - xs[1], d2 = xr[2] - xs[2];
    float d3 = xr3 - xs3,     d4 = xr[4] - xs[4], d5 = xr[5] - xs[5];
    float dist = sqrtf(d0 * d0 + d1 * d1 + d2 * d2);
    float inv = dist > 0.f ? 1.f / dist : 0.f;
    int slot = atomicAdd(ecnt, 1);
    ushort8 o;
    o[0] = f2b(d3); o[1] = f2b(d4); o[2] = f2b(d5); o[3] = f2b(dist);
    o[4] = f2b(d0 * inv); o[5] = f2b(d1 * inv); o[6] = f2b(d2 * inv); o[7] = 0;
    *(ushort8*)&e8u[(size_t)slot * 8] = o;
    cse[slot] = s;
    cre[slot] = r;
    atomicAdd(&deg[r], 1);
}

// ---------------- exclusive scan of deg -> rowptr (3 kernels) ----------------
__global__ __launch_bounds__(256) void scan_block_k(const int* __restrict__ deg,
    int* __restrict__ rowptr, int* __restrict__ bsum)
{
    __shared__ int s[256];
    const int tid = threadIdx.x;
    const int i = blockIdx.x * 256 + tid;
    const int v = (i < NN) ? deg[i] : 0;
    s[tid] = v;
    __syncthreads();
    for (int off = 1; off < 256; off <<= 1) {
        int t = (tid >= off) ? s[tid - off] : 0;
        __syncthreads();
        s[tid] += t;
        __syncthreads();
    }
    if (i < NN) rowptr[i] = s[tid] - v;        // block-local exclusive
    if (tid == 255) bsum[blockIdx.x] = s[255];
}

__global__ __launch_bounds__(256) void scan_top_k(int* __restrict__ bsum, int* __restrict__ boff)
{
    __shared__ int s[256];
    const int tid = threadIdx.x;
    const int v = (tid < NSB) ? bsum[tid] : 0;
    s[tid] = v;
    __syncthreads();
    for (int off = 1; off < 256; off <<= 1) {
        int t = (tid >= off) ? s[tid - off] : 0;
        __syncthreads();
        s[tid] += t;
        __syncthreads();
    }
    boff[tid] = s[tid] - v;                    // exclusive
}

__global__ __launch_bounds__(256) void scan_add_k(int* __restrict__ rowptr,
    const int* __restrict__ boff, int* __restrict__ cursor, const int* __restrict__ ecnt)
{
    const int i = blockIdx.x * 256 + threadIdx.x;
    if (i < NN) {
        const int r = rowptr[i] + boff[blockIdx.x];
        rowptr[i] = r;
        cursor[i] = r;
    }
    if (i == 0) rowptr[NN] = *ecnt;
}

// ---------------- fill CSR: edges sorted by recv ----------------
__global__ __launch_bounds__(256) void csr_fill_k(
    const int* __restrict__ cse, const int* __restrict__ cre, const int* __restrict__ ecnt,
    const unsigned short* __restrict__ e8u, int* __restrict__ cursor,
    int* __restrict__ csr_s, int* __restrict__ csr_r, unsigned short* __restrict__ e8c)
{
    const int i = blockIdx.x * 256 + threadIdx.x;
    if (i >= *ecnt) return;
    const int r = cre[i];
    const int pos = atomicAdd(&cursor[r], 1);
    csr_s[pos] = cse[i];
    csr_r[pos] = r;
    *(ushort8*)&e8c[(size_t)pos * 8] = *(const ushort8*)&e8u[(size_t)i * 8];
}

// ---------------- pack weights into MFMA fragment order ----------------
__global__ __launch_bounds__(256) void pack_w_k(
    const float* __restrict__ w, unsigned short* __restrict__ out,
    int KIN, int NT, int KT, int NCOL)
{
    int idx = blockIdx.x * 256 + threadIdx.x;
    int total = KT * NT * 512;
    if (idx >= total) return;
    int i = idx & 7;
    int lane = (idx >> 3) & 63;
    int t = idx >> 9;            // kt*NT + nt
    int nt = t % NT, kt = t / NT;
    int k = kt * 32 + (lane >> 4) * 8 + i;
    int n = nt * 16 + (lane & 15);
    out[idx] = (k < KIN) ? f2b(w[(size_t)k * NCOL + n]) : (unsigned short)0;
}

// ---------------- pack concatenated node weights Wcat = [W1a | W1b] (512 out cols) ----------------
// out col n<256: W1 rows [0,HD); n>=256: W1 rows [HD,2HD), col n-256.
__global__ __launch_bounds__(256) void pack_wcat_k(
    const float* __restrict__ w1, unsigned short* __restrict__ out, int HD, int KT)
{
    int idx = blockIdx.x * 256 + threadIdx.x;
    int total = KT * 32 * 512;
    if (idx >= total) return;
    int i = idx & 7;
    int lane = (idx >> 3) & 63;
    int t = idx >> 9;            // kt*32 + nt
    int nt = t & 31, kt = t >> 5;
    int k = kt * 32 + (lane >> 4) * 8 + i;
    int n = nt * 16 + (lane & 15);
    int row = k + (n < 256 ? 0 : HD);
    out[idx] = (k < HD) ? f2b(w1[(size_t)row * 256 + (n & 255)]) : (unsigned short)0;
}

// ---------------- dense node GEMM: Y[n][0:512] = h[n] @ [W1a | W1b]  (bf16 out, no bias) ----------------
// KT=1: hin = x [NN][6] fp32; KT=4: hin = h1 [NN][128] fp32 (converted to bf16 at staging).
template<int KT>
__global__ __launch_bounds__(256) void ygemm_k(
    const float* __restrict__ hin,
    const unsigned short* __restrict__ wcat,   // packed [KT][32][64][8]
    unsigned short* __restrict__ y)            // [NN][512]
{
    constexpr int KS = (KT == 1) ? 40 : 136;
    __shared__ unsigned short s_in[64][KS];
    const int tid = threadIdx.x;
    const int n0 = blockIdx.x * 64;
    { // stage: 4 threads/node, fp32 -> bf16
        const int ng = tid >> 2, p = tid & 3;
        const int n = n0 + ng;
        if constexpr (KT == 1) {
            ushort8 v = ushort8(0);
            if (p == 0 && n < NN) {
                const float* xr = hin + (size_t)n * 6;
                v[0] = f2b(xr[0]); v[1] = f2b(xr[1]); v[2] = f2b(xr[2]);
                v[3] = f2b(xr[3]); v[4] = f2b(xr[4]); v[5] = f2b(xr[5]);
            }
            *(ushort8*)&s_in[ng][p * 8] = v;    // cols 0..31 (zeros past 5)
        } else {
            unsigned short u[32];
            #pragma unroll
            for (int c = 0; c < 32; ++c) u[c] = 0;
            if (n < NN) {
                const float* src = hin + (size_t)n * 128 + p * 32;
                #pragma unroll
                for (int k = 0; k < 8; ++k) {
                    const float4 v = *(const float4*)(src + k * 4);
                    u[k*4] = f2b(v.x); u[k*4+1] = f2b(v.y); u[k*4+2] = f2b(v.z); u[k*4+3] = f2b(v.w);
                }
            }
            #pragma unroll
            for (int k = 0; k < 4; ++k)
                *(ushort8*)&s_in[ng][p * 32 + k * 8] = *(ushort8*)&u[k * 8];
        }
    }
    __syncthreads();

    const int wv = tid >> 6, lane = tid & 63, lhi = lane >> 4, llo = lane & 15;
    const short8* wf = (const short8*)wcat;
    // wave wv owns out cols [wv*128, wv*128+128): mt 0..7; nt = node tile 0..3
    f32x4 acc[8][4];
    #pragma unroll
    for (int mt = 0; mt < 8; ++mt)
        #pragma unroll
        for (int nt = 0; nt < 4; ++nt) acc[mt][nt] = f32x4{0.f, 0.f, 0.f, 0.f};
    #pragma unroll
    for (int kt = 0; kt < KT; ++kt) {
        short8 bf[4];
        #pragma unroll
        for (int nt = 0; nt < 4; ++nt)
            bf[nt] = *(const short8*)&s_in[nt * 16 + llo][kt * 32 + lhi * 8];
        #pragma unroll
        for (int mt = 0; mt < 8; ++mt) {
            const short8 aw = wf[(kt * 32 + wv * 8 + mt) * 64 + lane];
            #pragma unroll
            for (int nt = 0; nt < 4; ++nt)
                acc[mt][nt] = __builtin_amdgcn_mfma_f32_16x16x32_bf16(aw, bf[nt], acc[mt][nt], 0, 0, 0);
        }
    }
    // write: D^T layout -> Y[node][col], col = wv*128 + mt*16 + lhi*4 + r, node = n0 + nt*16 + llo
    #pragma unroll
    for (int mt = 0; mt < 8; ++mt)
        #pragma unroll
        for (int nt = 0; nt < 4; ++nt) {
            const int n = n0 + nt * 16 + llo;
            if (n < NN) {
                ushort4 v;
                v.x = f2b(acc[mt][nt][0]); v.y = f2b(acc[mt][nt][1]);
                v.z = f2b(acc[mt][nt][2]); v.w = f2b(acc[mt][nt][3]);
                *(ushort4*)&y[(size_t)n * 512 + wv * 128 + mt * 16 + lhi * 4] = v;
            }
        }
}

// ---------------- unified edge kernel: t = relu(Ya[r]+Yb[s]+e@We+b1) -> layer2 MFMA -> scatter ----------------
__global__ __launch_bounds__(256) void edge_k(
    const unsigned short* __restrict__ y,      // [NN][512] bf16
    const unsigned short* __restrict__ e8c,    // [NE][8] bf16, CSR order
    const float* __restrict__ we,              // e-part weights [7][256] fp32 (row stride 256)
    const float* __restrict__ b1,              // [256]
    const int* __restrict__ csr_s, const int* __restrict__ csr_r, const int* __restrict__ ecnt,
    const unsigned short* __restrict__ w2s, const float* __restrict__ b2,   // packed [8][8][64][8], [128]
    float* __restrict__ hout)                                               // [NN,128] zeroed
{
    extern __shared__ char smem[];
    char* s_tf = smem;                         // 32768 B: t bf16 [64][256] <-> out f32 [64][128]
    int* s_recv = (int*)(smem + 32768);

    const int Ec = *ecnt;
    const int e0 = blockIdx.x * 64;
    if (e0 >= Ec) return;
    const int tid = threadIdx.x;
    const int wv = tid >> 6, lane = tid & 63, lhi = lane >> 4, llo = lane & 15;
    const short8* w2f = (const short8*)w2s;

    { // ---- phase 0: build t directly into swizzled LDS; 4 threads/edge, 64 cols each ----
        const int eg = tid >> 2, p = tid & 3;
        const int e = e0 + eg;
        const bool ev = e < Ec;
        int s = 0, r = 0;
        if (ev) { s = csr_s[e]; r = csr_r[e]; }
        if (p == 0) s_recv[eg] = r;
        float ef[7];
        #pragma unroll
        for (int k = 0; k < 7; ++k) ef[k] = 0.f;
        if (ev) {
            #pragma unroll
            for (int k = 0; k < 7; ++k) ef[k] = b2f(e8c[(size_t)e * 8 + k]);
        }
        #pragma unroll
        for (int hh = 0; hh < 2; ++hh) {
            const int c0 = p * 64 + hh * 32;
            float t[32];
            #pragma unroll
            for (int g = 0; g < 8; ++g) {
                const float4 bv = *(const float4*)(b1 + c0 + g * 4);
                t[g*4] = bv.x; t[g*4+1] = bv.y; t[g*4+2] = bv.z; t[g*4+3] = bv.w;
            }
            if (ev) {
                const unsigned short* ya = y + (size_t)r * 512 + c0;
                const unsigned short* yb = y + (size_t)s * 512 + 256 + c0;
                #pragma unroll
                for (int g = 0; g < 4; ++g) {
                    const ushort8 a = *(const ushort8*)(ya + g * 8);
                    const ushort8 b = *(const ushort8*)(yb + g * 8);
                    #pragma unroll
                    for (int j = 0; j < 8; ++j) t[g*8+j] += b2f(a[j]) + b2f(b[j]);
                }
                #pragma unroll
                for (int k = 0; k < 7; ++k) {
                    const float* wr = we + (size_t)k * 256 + c0;
                    #pragma unroll
                    for (int g = 0; g < 8; ++g) {
                        const float4 wv4 = *(const float4*)(wr + g * 4);
                        t[g*4]   += ef[k] * wv4.x; t[g*4+1] += ef[k] * wv4.y;
                        t[g*4+2] += ef[k] * wv4.z; t[g*4+3] += ef[k] * wv4.w;
                    }
                }
            }
            #pragma unroll
            for (int g = 0; g < 4; ++g) {
                ushort8 o;
                #pragma unroll
                for (int j = 0; j < 8; ++j) o[j] = f2b(fmaxf(t[g*8+j], 0.f));
                *(ushort8*)(s_tf + swz(eg, (c0 + g * 8) * 2)) = o;
            }
        }
    }
    __syncthreads();

    // ---- phase 1: layer 2  D2^T[128 out][64 edge] = W2-packed x T^T ----
    f32x4 acc2[2][4];
    #pragma unroll
    for (int q = 0; q < 2; ++q) {
        const f32x4 bv = *(const f32x4*)&b2[wv * 32 + q * 16 + lhi * 4];
        #pragma unroll
        for (int nt = 0; nt < 4; ++nt) acc2[q][nt] = bv;
    }
    #pragma unroll
    for (int kt = 0; kt < 8; ++kt) {
        short8 bt[4];
        #pragma unroll
        for (int nt = 0; nt < 4; ++nt)
            bt[nt] = *(const short8*)(s_tf + swz(nt * 16 + llo, kt * 64 + lhi * 16));
        #pragma unroll
        for (int q = 0; q < 2; ++q) {
            const short8 aw = w2f[(kt * 8 + wv * 2 + q) * 64 + lane];
            #pragma unroll
            for (int nt = 0; nt < 4; ++nt)
                acc2[q][nt] = __builtin_amdgcn_mfma_f32_16x16x32_bf16(aw, bt[nt], acc2[q][nt], 0, 0, 0);
        }
    }
    __syncthreads();                 // all t reads done before f32 overlay writes

    // ---- phase 2: relu -> f32 out tile in LDS ----
    #pragma unroll
    for (int q = 0; q < 2; ++q)
        #pragma unroll
        for (int nt = 0; nt < 4; ++nt) {
            const int row = nt * 16 + llo;
            const int o0 = wv * 32 + q * 16 + lhi * 4;
            float4 v = make_float4(fmaxf(acc2[q][nt][0], 0.f), fmaxf(acc2[q][nt][1], 0.f),
                                   fmaxf(acc2[q][nt][2], 0.f), fmaxf(acc2[q][nt][3], 0.f));
            *(float4*)(s_tf + swz(row, o0 * 4)) = v;
        }
    __syncthreads();

    // ---- phase 3: run-segmented scatter (edges sorted by recv) ----
    {
        const int c = tid & 127, hf = tid >> 7;
        int cur = -1; float run = 0.f;
        for (int i = 0; i < 32; ++i) {
            const int row = hf * 32 + i;
            if (e0 + row >= Ec) break;
            const int rv = s_recv[row];
            const float val = *(const float*)(s_tf + swz(row, c * 4));
            if (rv != cur) {
                if (cur >= 0) unsafeAtomicAdd(&hout[(size_t)cur * 128 + c], run);
                cur = rv; run = 0.f;
            }
            run += val;
        }
        if (cur >= 0) unsafeAtomicAdd(&hout[(size_t)cur * 128 + c], run);
    }
}

// ---------------- node update MLP via MFMA: 128 -> 128 -> 64 ----------------
__global__ __launch_bounds__(256) void upd_mfma_k(
    const float* __restrict__ hin,                                         // [NN,128] fp32
    const unsigned short* __restrict__ w1p, const float* __restrict__ b1,  // packed [4][8][64][8]
    const unsigned short* __restrict__ w2p, const float* __restrict__ b2,  // packed [4][4][64][8]
    float* __restrict__ hout)                                              // [NN,64]
{
    __shared__ unsigned short s_in[64][136];
    __shared__ unsigned short s_t[64][136];
    const int tid = threadIdx.x;
    const int n0 = blockIdx.x * 64;

    { // stage: 4 threads/node, 32 cols each, fp32 -> bf16
        const int ng = tid >> 2, p = tid & 3;
        const int n = n0 + ng;
        if (n < NN) {
            const float* src = hin + (size_t)n * 128 + p * 32;
            unsigned short u[32];
            #pragma unroll
            for (int k = 0; k < 8; ++k) {
                const float4 v = *(const float4*)(src + k * 4);
                u[k*4] = f2b(v.x); u[k*4+1] = f2b(v.y); u[k*4+2] = f2b(v.z); u[k*4+3] = f2b(v.w);
            }
            #pragma unroll
            for (int k = 0; k < 4; ++k)
                *(ushort8*)&s_in[ng][p * 32 + k * 8] = *(ushort8*)&u[k * 8];
        } else {
            #pragma unroll
            for (int k = 0; k < 4; ++k)
                *(ushort8*)&s_in[ng][p * 32 + k * 8] = ushort8(0);
        }
    }
    __syncthreads();

    const int wv = tid >> 6, lane = tid & 63, lhi = lane >> 4, llo = lane & 15;
    const short8* w1f = (const short8*)w1p;
    const short8* w2f = (const short8*)w2p;

    { // layer1: [64,128]x[128,128]; wave wv owns cols wv*32..+31
        f32x4 acc[2][4];
        #pragma unroll
        for (int q = 0; q < 2; ++q) {
            const float bv = b1[(wv * 2 + q) * 16 + llo];
            #pragma unroll
            for (int mt = 0; mt < 4; ++mt) acc[q][mt] = f32x4{bv, bv, bv, bv};
        }
        #pragma unroll
        for (int kt = 0; kt < 4; ++kt) {
            short8 af[4];
            #pragma unroll
            for (int mt = 0; mt < 4; ++mt)
                af[mt] = *(const short8*)&s_in[mt * 16 + llo][kt * 32 + lhi * 8];
            #pragma unroll
            for (int q = 0; q < 2; ++q) {
                const short8 bf = w1f[(kt * 8 + wv * 2 + q) * 64 + lane];
                #pragma unroll
                for (int mt = 0; mt < 4; ++mt)
                    acc[q][mt] = __builtin_amdgcn_mfma_f32_16x16x32_bf16(af[mt], bf, acc[q][mt], 0, 0, 0);
            }
        }
        #pragma unroll
        for (int q = 0; q < 2; ++q)
            #pragma unroll
            for (int mt = 0; mt < 4; ++mt)
                #pragma unroll
                for (int r = 0; r < 4; ++r)
                    s_t[mt * 16 + lhi * 4 + r][(wv * 2 + q) * 16 + llo] =
                        f2b(fmaxf(acc[q][mt][r], 0.f));
    }
    __syncthreads();

    { // layer2: [64,128]x[128,64]; wave wv owns cols wv*16..+15
        f32x4 acc[4];
        const float bv = b2[wv * 16 + llo];
        #pragma unroll
        for (int mt = 0; mt < 4; ++mt) acc[mt] = f32x4{bv, bv, bv, bv};
        #pragma unroll
        for (int kt = 0; kt < 4; ++kt) {
            short8 af[4];
            #pragma unroll
            for (int mt = 0; mt < 4; ++mt)
                af[mt] = *(const short8*)&s_t[mt * 16 + llo][kt * 32 + lhi * 8];
            const short8 bf = w2f[(kt * 4 + wv) * 64 + lane];
            #pragma unroll
            for (int mt = 0; mt < 4; ++mt)
                acc[mt] = __builtin_amdgcn_mfma_f32_16x16x32_bf16(af[mt], bf, acc[mt], 0, 0, 0);
        }
        #pragma unroll
        for (int mt = 0; mt < 4; ++mt)
            #pragma unroll
            for (int r = 0; r < 4; ++r) {
                const int n = n0 + mt * 16 + lhi * 4 + r;
                if (n < NN)
                    hout[(size_t)n * 64 + wv * 16 + llo] = fmaxf(acc[mt][r], 0.f);
            }
    }
}

// ---------------- SAGE: inline CSR gather-mean + MFMA transform + l2norm + pooled reduce ----------------
__global__ __launch_bounds__(256) void sage_node_k(
    const float* __restrict__ hu,                       // [NN,64]
    const int* __restrict__ rowptr, const int* __restrict__ csr_s,
    const int* __restrict__ seg,
    const unsigned short* __restrict__ wss, const float* __restrict__ sb,  // packed [4][8][64][8]
    float* __restrict__ pmax, float* __restrict__ psum, float* __restrict__ npn)
{
    __shared__ unsigned short s_in[64][136];
    __shared__ float s_g[64][130];
    __shared__ float s_inv[64];
    __shared__ int   s_seg[64];
    const int tid = threadIdx.x;
    const int n0 = blockIdx.x * 64;

    { // ---- stage: 4 threads/node, 16 cols each; gather neighbor mean from CSR ----
        const int ng = tid >> 2, p = tid & 3;
        const int n = n0 + ng;
        if (n < NN) {
            if (p == 0) s_seg[ng] = seg[n];
            const float* hr = hu + (size_t)n * 64 + p * 16;
            float a[16];
            #pragma unroll
            for (int k = 0; k < 4; ++k) {
                const float4 v = *(const float4*)(hr + k * 4);
                a[k*4] = v.x; a[k*4+1] = v.y; a[k*4+2] = v.z; a[k*4+3] = v.w;
            }
            float s[16];
            #pragma unroll
            for (int k = 0; k < 16; ++k) s[k] = 0.f;
            const int rb = rowptr[n], re = rowptr[n + 1];
            for (int e = rb; e < re; ++e) {
                const float* hs = hu + (size_t)csr_s[e] * 64 + p * 16;
                #pragma unroll
                for (int k = 0; k < 4; ++k) {
                    const float4 v = *(const float4*)(hs + k * 4);
                    s[k*4] += v.x; s[k*4+1] += v.y; s[k*4+2] += v.z; s[k*4+3] += v.w;
                }
            }
            const float inv = (re > rb) ? 1.f / (float)(re - rb) : 0.f;
            unsigned short uh[16], ua[16];
            #pragma unroll
            for (int k = 0; k < 16; ++k) { uh[k] = f2b(a[k]); ua[k] = f2b(s[k] * inv); }
            *(ushort8*)&s_in[ng][p * 16]          = *(ushort8*)&uh[0];
            *(ushort8*)&s_in[ng][p * 16 + 8]      = *(ushort8*)&uh[8];
            *(ushort8*)&s_in[ng][64 + p * 16]     = *(ushort8*)&ua[0];
            *(ushort8*)&s_in[ng][64 + p * 16 + 8] = *(ushort8*)&ua[8];
        } else {
            if (p == 0) s_seg[ng] = -1;
            *(ushort8*)&s_in[ng][p * 16]          = ushort8(0);
            *(ushort8*)&s_in[ng][p * 16 + 8]      = ushort8(0);
            *(ushort8*)&s_in[ng][64 + p * 16]     = ushort8(0);
            *(ushort8*)&s_in[ng][64 + p * 16 + 8] = ushort8(0);
        }
    }
    __syncthreads();

    const int wv = tid >> 6, lane = tid & 63, lhi = lane >> 4, llo = lane & 15;
    const short8* wf = (const short8*)wss;
    { // ---- [64,128] x [128,128] MFMA; wave wv owns cols wv*32..wv*32+31 ----
        f32x4 acc[2][4];
        #pragma unroll
        for (int q = 0; q < 2; ++q) {
            const float bv = sb[(wv * 2 + q) * 16 + llo];
            #pragma unroll
            for (int mt = 0; mt < 4; ++mt) acc[q][mt] = f32x4{bv, bv, bv, bv};
        }
        #pragma unroll
        for (int kt = 0; kt < 4; ++kt) {
            short8 af[4];
            #pragma unroll
            for (int mt = 0; mt < 4; ++mt)
                af[mt] = *(const short8*)&s_in[mt * 16 + llo][kt * 32 + lhi * 8];
            #pragma unroll
            for (int q = 0; q < 2; ++q) {
                const short8 bf = wf[(kt * 8 + wv * 2 + q) * 64 + lane];
                #pragma unroll
                for (int mt = 0; mt < 4; ++mt)
                    acc[q][mt] = __builtin_amdgcn_mfma_f32_16x16x32_bf16(af[mt], bf, acc[q][mt], 0, 0, 0);
            }
        }
        #pragma unroll
        for (int q = 0; q < 2; ++q)
            #pragma unroll
            for (int mt = 0; mt < 4; ++mt)
                #pragma unroll
                for (int r = 0; r < 4; ++r)
                    s_g[mt * 16 + lhi * 4 + r][(wv * 2 + q) * 16 + llo] = acc[q][mt][r];
    }
    __syncthreads();
    { // ---- l2 norm (pre-relu, fp32): 4 threads/row ----
        const int row = tid >> 2, p = tid & 3;
        float ss = 0.f;
        #pragma unroll
        for (int k = 0; k < 32; ++k) { const float v = s_g[row][p * 32 + k]; ss += v * v; }
        ss += __shfl_xor(ss, 1);
        ss += __shfl_xor(ss, 2);
        if (p == 0) s_inv[row] = rsqrtf(fmaxf(ss, 1e-12f));
    }
    __syncthreads();
    { // ---- run-segmented pooling: seg sorted -> one atomic pair per run per col ----
        const int c = tid & 127, hf = tid >> 7;
        int cur = -1; float rs = 0.f, rm = 0.f;     // g >= 0, so 0 is a valid max identity
        for (int i = 0; i < 32; ++i) {
            const int row = hf * 32 + i;
            if (n0 + row >= NN) break;
            const int sg = s_seg[row];
            const float g = fmaxf(s_g[row][c] * s_inv[row], 0.f);
            if (sg != cur) {
                if (cur >= 0) {
                    unsafeAtomicAdd(&psum[(size_t)cur * 128 + c], rs);
                    atomicMax((unsigned int*)&pmax[(size_t)cur * 128 + c], __float_as_uint(rm));
                }
                cur = sg; rs = 0.f; rm = 0.f;
            }
            rs += g; rm = fmaxf(rm, g);
        }
        if (cur >= 0) {
            unsafeAtomicAdd(&psum[(size_t)cur * 128 + c], rs);
            atomicMax((unsigned int*)&pmax[(size_t)cur * 128 + c], __float_as_uint(rm));
        }
    }
    if (tid == 0 || tid == 128) { // ---- npn: node counts per run ----
        const int hf = tid >> 7;
        int cur = -1; float cnt = 0.f;
        for (int i = 0; i < 32; ++i) {
            const int row = hf * 32 + i;
            if (n0 + row >= NN) break;
            const int sg = s_seg[row];
            if (sg != cur) { if (cur >= 0) unsafeAtomicAdd(&npn[cur], cnt); cur = sg; cnt = 0.f; }
            cnt += 1.f;
        }
        if (cur >= 0) unsafeAtomicAdd(&npn[cur], cnt);
    }
}

// ---------------- decoder + heads ----------------
__global__ __launch_bounds__(256) void dec_heads_k(
    const float* __restrict__ pmax, const float* __restrict__ psum, const float* __restrict__ npn,
    const float* __restrict__ d0w, const float* __restrict__ d0b,
    const float* __restrict__ g0, const float* __restrict__ be0,
    const float* __restrict__ m0, const float* __restrict__ v0,
    const float* __restrict__ d1w, const float* __restrict__ d1b,
    const float* __restrict__ g1, const float* __restrict__ be1,
    const float* __restrict__ m1, const float* __restrict__ v1,
    const float* __restrict__ lw0, const float* __restrict__ lb0,
    const float* __restrict__ lw1, const float* __restrict__ lb1,
    const float* __restrict__ lwo, const float* __restrict__ lbo,
    const float* __restrict__ aw0, const float* __restrict__ ab0,
    const float* __restrict__ aw1, const float* __restrict__ ab1,
    const float* __restrict__ awo, const float* __restrict__ abo,
    const float* __restrict__ sw0, const float* __restrict__ sb0,
    const float* __restrict__ sw1, const float* __restrict__ sb1,
    const float* __restrict__ swo, const float* __restrict__ sbo,
    const float* __restrict__ ascw, const float* __restrict__ ascb,
    float* __restrict__ out)
{
    __shared__ float z0[384];
    __shared__ float z1[1024];
    __shared__ float z2[512];
    __shared__ float ha[192];
    __shared__ float hb[192];
    __shared__ float fin[8];
    const int b = blockIdx.x, tid = threadIdx.x;
    if (tid < 128) {
        const float pm = pmax[(size_t)b * 128 + tid];
        const float ps = psum[(size_t)b * 128 + tid];
        const float nv = fmaxf(npn[b], 1.f);
        z0[tid] = pm; z0[128 + tid] = ps / nv; z0[256 + tid] = ps;
    }
    __syncthreads();
    {
        float acc[4] = { d0b[tid], d0b[tid + 256], d0b[tid + 512], d0b[tid + 768] };
        for (int k = 0; k < 384; ++k) {
            const float zk = z0[k];
            const float* wr = d0w + (size_t)k * 1024 + tid;
            acc[0] += zk * wr[0]; acc[1] += zk * wr[256]; acc[2] += zk * wr[512]; acc[3] += zk * wr[768];
        }
        #pragma unroll
        for (int i = 0; i < 4; ++i) {
            const int j = tid + 256 * i;
            float v = acc[i] > 0.f ? acc[i] : 0.15f * acc[i];
            v = (v - m0[j]) * (1.f / sqrtf(v0[j] + 1e-3f)) * g0[j] + be0[j];
            z1[j] = v;
        }
    }
    __syncthreads();
    {
        float acc[2] = { d1b[tid], d1b[tid + 256] };
        for (int k = 0; k < 1024; ++k) {
            const float zk = z1[k];
            const float* wr = d1w + (size_t)k * 512 + tid;
            acc[0] += zk * wr[0]; acc[1] += zk * wr[256];
        }
        #pragma unroll
        for (int i = 0; i < 2; ++i) {
            const int j = tid + 256 * i;
            float v = acc[i] > 0.f ? acc[i] : 0.15f * acc[i];
            v = (v - m1[j]) * (1.f / sqrtf(v1[j] + 1e-3f)) * g1[j] + be1[j];
            z2[j] = v;
        }
    }
    __syncthreads();
    if (tid < 192) {
        const int hd = tid >> 6, j = tid & 63;
        const float* w0 = hd == 0 ? lw0 : (hd == 1 ? aw0 : sw0);
        const float* b0 = hd == 0 ? lb0 : (hd == 1 ? ab0 : sb0);
        float acc = b0[j];
        for (int k = 0; k < 512; ++k) acc += z2[k] * w0[(size_t)k * 64 + j];
        ha[tid] = acc;
    }
    __syncthreads();
    if (tid < 192) {
        const int hd = tid >> 6, j = tid & 63;
        const float* w1p = hd == 0 ? lw1 : (hd == 1 ? aw1 : sw1);
        const float* b1p = hd == 0 ? lb1 : (hd == 1 ? ab1 : sb1);
        const float* src = &ha[hd * 64];
        float acc = b1p[j];
        for (int k = 0; k < 64; ++k) acc += src[k] * w1p[(size_t)k * 64 + j];
        hb[tid] = acc;
    }
    __syncthreads();
    if (tid < 5) {
        float acc;
        if (tid == 0) { acc = lbo[0]; for (int k = 0; k < 64; ++k) acc += hb[k] * lwo[k]; }
        else if (tid < 3) { const int c = tid - 1; acc = abo[c]; for (int k = 0; k < 64; ++k) acc += hb[64 + k] * awo[k * 2 + c]; }
        else { const int c = tid - 3; acc = sbo[c]; for (int k = 0; k < 64; ++k) acc += hb[128 + k] * swo[k * 2 + c]; }
        fin[tid] = acc;
    }
    __syncthreads();
    if (tid == 0) {
        const float a0 = fin[1], a1 = fin[2];
        const float q0 = a0 * ascw[0] + a1 * ascw[2] + ascb[0];
        const float q1 = a0 * ascw[1] + a1 * ascw[3] + ascb[1];
        const float zen = 1.f / (1.f + expf(-q0));
        const float azi = 1.f / (1.f + expf(-q1));
        const float PI = 3.14159265358979323846f;
        float* o = out + (size_t)b * 5;
        o[0] = fin[0];
        o[1] = zen * PI;
        o[2] = azi * 2.f * PI;
        o[3] = fabsf(fin[3]) + 1e-5f;
        o[4] = fabsf(fin[4]) + 1e-5f;
    }
}

extern "C" void kernel_launch(void* const* d_in, const int* in_sizes, int n_in,
                              void* d_out, int out_size, void* d_ws, size_t ws_size,
                              hipStream_t stream)
{
    const float* x    = (const float*)d_in[0];
    const int* send   = (const int*)d_in[1];
    const int* recv   = (const int*)d_in[2];
    const int* seg    = (const int*)d_in[3];
    const float* m0w1 = (const float*)d_in[4];
    const float* m0b1 = (const float*)d_in[5];
    const float* m0w2 = (const float*)d_in[6];
    const float* m0b2 = (const float*)d_in[7];
    const float* m1w1 = (const float*)d_in[8];
    const float* m1b1 = (const float*)d_in[9];
    const float* m1w2 = (const float*)d_in[10];
    const float* m1b2 = (const float*)d_in[11];
    const float* uw1  = (const float*)d_in[12];
    const float* ub1  = (const float*)d_in[13];
    const float* uw2  = (const float*)d_in[14];
    const float* ub2  = (const float*)d_in[15];
    const float* sgw  = (const float*)d_in[16];
    const float* sgb  = (const float*)d_in[17];
    const float* d0w  = (const float*)d_in[18];
    const float* d0b  = (const float*)d_in[19];
    const float* bn0g = (const float*)d_in[20];
    const float* bn0b = (const float*)d_in[21];
    const float* bn0m = (const float*)d_in[22];
    const float* bn0v = (const float*)d_in[23];
    const float* d1w  = (const float*)d_in[24];
    const float* d1b  = (const float*)d_in[25];
    const float* bn1g = (const float*)d_in[26];
    const float* bn1b = (const float*)d_in[27];
    const float* bn1m = (const float*)d_in[28];
    const float* bn1v = (const float*)d_in[29];
    const float* lw0  = (const float*)d_in[30];
    const float* lb0  = (const float*)d_in[31];
    const float* lw1  = (const float*)d_in[32];
    const float* lb1  = (const float*)d_in[33];
    const float* lwo  = (const float*)d_in[34];
    const float* lbo  = (const float*)d_in[35];
    const float* aw0  = (const float*)d_in[36];
    const float* ab0  = (const float*)d_in[37];
    const float* aw1  = (const float*)d_in[38];
    const float* ab1  = (const float*)d_in[39];
    const float* awo  = (const float*)d_in[40];
    const float* abo  = (const float*)d_in[41];
    const float* sw0  = (const float*)d_in[42];
    const float* sb0  = (const float*)d_in[43];
    const float* sw1  = (const float*)d_in[44];
    const float* sb1  = (const float*)d_in[45];
    const float* swo  = (const float*)d_in[46];
    const float* sbo  = (const float*)d_in[47];
    const float* ascw = (const float*)d_in[48];
    const float* ascb = (const float*)d_in[49];

    char* ws = (char*)d_ws;
    size_t off = 0;
    auto alloc = [&](size_t bytes) { void* p = ws + off; off = (off + bytes + 31) & ~(size_t)31; return p; };
    // zero-region: h1,h2,pmax,psum,npn contiguous
    float* h1   = (float*)alloc((size_t)NN * 128 * 4);
    float* h2   = (float*)alloc((size_t)NN * 128 * 4);
    float* pmax = (float*)alloc((size_t)NB * 128 * 4);
    float* psum = (float*)alloc((size_t)NB * 128 * 4);
    float* npn  = (float*)alloc((size_t)NB * 4);
    // Y region (61.44MB) unions the pre-CSR temporaries (all dead before ygemm0 writes Y)
    char* yreg  = (char*)alloc((size_t)NN * 512 * 2);
    unsigned short* Y   = (unsigned short*)yreg;
    unsigned short* e8u = (unsigned short*)yreg;                    // [NE][8] bf16
    int* cse    = (int*)(yreg + (size_t)NE * 8 * 2);                // [NE]
    int* cre    = cse + NE;                                         // [NE]
    int* deg    = cre + NE;                                         // [NN]
    int* cursor = deg + NN;                                         // [NN]
    unsigned short* e8c = (unsigned short*)alloc((size_t)NE * 8 * 2);
    int* csr_s  = (int*)alloc((size_t)NE * 4);
    int* csr_r  = (int*)alloc((size_t)NE * 4);
    int* rowptr = (int*)alloc((size_t)(NN + 1) * 4);
    int* bsum   = (int*)alloc(256 * 4);
    int* boff   = (int*)alloc(256 * 4);
    int* ecnt   = (int*)alloc(4);
    unsigned short* wc0  = (unsigned short*)alloc((size_t)1 * 32 * 512 * 2);
    unsigned short* wc1  = (unsigned short*)alloc((size_t)4 * 32 * 512 * 2);
    unsigned short* w2s0 = (unsigned short*)alloc((size_t)8 * 8 * 512 * 2);
    unsigned short* w2s1 = (unsigned short*)alloc((size_t)8 * 8 * 512 * 2);
    unsigned short* wss  = (unsigned short*)alloc((size_t)4 * 8 * 512 * 2);
    unsigned short* wup1 = (unsigned short*)alloc((size_t)4 * 8 * 512 * 2);
    unsigned short* wup2 = (unsigned short*)alloc((size_t)4 * 4 * 512 * 2);
    float* hu = h1;                                   // [N,64] (h1 dead after ygemm1)

    hipMemsetAsync(h1, 0, ((size_t)NN * 256 + (size_t)NB * 257) * sizeof(float), stream);
    hipMemsetAsync(deg, 0, (size_t)NN * sizeof(int), stream);
    hipMemsetAsync(ecnt, 0, sizeof(int), stream);

    pack_wcat_k<<<(1 * 32 * 512 + 255) / 256, 256, 0, stream>>>(m0w1, wc0, 6, 1);
    pack_wcat_k<<<(4 * 32 * 512 + 255) / 256, 256, 0, stream>>>(m1w1, wc1, 128, 4);
    pack_w_k<<<(8 * 8 * 512 + 255) / 256, 256, 0, stream>>>(m0w2, w2s0, 256, 8, 8, 128);
    pack_w_k<<<(8 * 8 * 512 + 255) / 256, 256, 0, stream>>>(m1w2, w2s1, 256, 8, 8, 128);
    pack_w_k<<<(4 * 8 * 512 + 255) / 256, 256, 0, stream>>>(sgw, wss, 128, 8, 4, 128);
    pack_w_k<<<(4 * 8 * 512 + 255) / 256, 256, 0, stream>>>(uw1, wup1, 128, 8, 4, 128);
    pack_w_k<<<(4 * 4 * 512 + 255) / 256, 256, 0, stream>>>(uw2, wup2, 128, 4, 4, 64);

    edge_compact_k<<<(NE + 255) / 256, 256, 0, stream>>>(x, send, recv, e8u, cse, cre, ecnt, deg);
    scan_block_k<<<NSB, 256, 0, stream>>>(deg, rowptr, bsum);
    scan_top_k<<<1, 256, 0, stream>>>(bsum, boff);
    scan_add_k<<<NSB, 256, 0, stream>>>(rowptr, boff, cursor, ecnt);
    csr_fill_k<<<(NE + 255) / 256, 256, 0, stream>>>(cse, cre, ecnt, e8u, cursor, csr_s, csr_r, e8c);

    // hop 0: dense Y = x @ [W1a|W1b], then edge MLP
    ygemm_k<1><<<(NN + 63) / 64, 256, 0, stream>>>(x, wc0, Y);
    edge_k<<<NE / 64, 256, 32768 + 256, stream>>>(
        Y, e8c, m0w1 + 12 * 256, m0b1, csr_s, csr_r, ecnt, w2s0, m0b2, h1);
    // hop 1: dense Y = h1 @ [W1a|W1b] (fp32 read, bf16 staged), then edge MLP
    ygemm_k<4><<<(NN + 63) / 64, 256, 0, stream>>>(h1, wc1, Y);
    edge_k<<<NE / 64, 256, 32768 + 256, stream>>>(
        Y, e8c, m1w1 + 256 * 256, m1b1, csr_s, csr_r, ecnt, w2s1, m1b2, h2);

    upd_mfma_k<<<(NN + 63) / 64, 256, 0, stream>>>(h2, wup1, ub1, wup2, ub2, hu);
    sage_node_k<<<(NN + 63) / 64, 256, 0, stream>>>(hu, rowptr, csr_s, seg, wss, sgb, pmax, psum, npn);
    dec_heads_k<<<NB, 256, 0, stream>>>(pmax, psum, npn,
        d0w, d0b, bn0g, bn0b, bn0m, bn0v,
        d1w, d1b, bn1g, bn1b, bn1m, bn1v,
        lw0, lb0, lw1, lb1, lwo, lbo,
        aw0, ab0, aw1, ab1, awo, abo,
        sw0, sb0, sw1, sb1, swo, sbo,
        ascw, ascb, (float*)d_out);
}

// Round 9
// 585.245 us; speedup vs baseline: 1.6946x; 1.6946x over previous
//
#include <hip/hip_runtime.h>
#include <hip/hip_bf16.h>
#include <math.h>

constexpr int NN = 60000;   // nodes
constexpr int NE = 480000;  // edges
constexpr int NB = 128;     // graphs
constexpr int NSB = (NN + 255) / 256;   // scan blocks = 235

typedef __attribute__((ext_vector_type(8))) short  short8;
typedef __attribute__((ext_vector_type(8))) unsigned short ushort8;
typedef __attribute__((ext_vector_type(4))) float  f32x4;

__device__ __forceinline__ unsigned short f2b(float x) {
    __hip_bfloat16 h = __float2bfloat16(x);   // RNE
    return *reinterpret_cast<unsigned short*>(&h);
}
// swizzled byte offset into a [64][512B] LDS tile: XOR 16B-chunk with row&7 (T2, G4)
__device__ __forceinline__ int swz(int row, int byte_in_row) {
    return row * 512 + (byte_in_row ^ ((row & 7) << 4));
}

// ---------------- edge features (bf16) + forward-in-time compaction + deg histogram ----------------
__global__ __launch_bounds__(256) void edge_compact_k(
    const float* __restrict__ x, const int* __restrict__ send, const int* __restrict__ recv,
    unsigned short* __restrict__ e8u, int* __restrict__ cse, int* __restrict__ cre,
    int* __restrict__ ecnt, int* __restrict__ deg)
{
    int e = blockIdx.x * 256 + threadIdx.x;
    if (e >= NE) return;
    int s = send[e], r = recv[e];
    const float* xs = x + (size_t)s * 6;
    const float* xr = x + (size_t)r * 6;
    float xs3 = xs[3], xr3 = xr[3];
    if (!(xs3 <= xr3)) return;                 // masked edge contributes nothing anywhere
    float d0 = xr[0] - xs[0], d1 = xr[1] - xs[1], d2 = xr[2] - xs[2];
    float d3 = xr3 - xs3,     d4 = xr[4] - xs[4], d5 = xr[5] - xs[5];
    float dist = sqrtf(d0 * d0 + d1 * d1 + d2 * d2);
    float inv = dist > 0.f ? 1.f / dist : 0.f;
    int slot = atomicAdd(ecnt, 1);
    ushort8 o;
    o[0] = f2b(d3); o[1] = f2b(d4); o[2] = f2b(d5); o[3] = f2b(dist);
    o[4] = f2b(d0 * inv); o[5] = f2b(d1 * inv); o[6] = f2b(d2 * inv); o[7] = 0;
    *(ushort8*)&e8u[(size_t)slot * 8] = o;
    cse[slot] = s;
    cre[slot] = r;
    atomicAdd(&deg[r], 1);
}

// ---------------- exclusive scan of deg -> rowptr (3 kernels) ----------------
__global__ __launch_bounds__(256) void scan_block_k(const int* __restrict__ deg,
    int* __restrict__ rowptr, int* __restrict__ bsum)
{
    __shared__ int s[256];
    const int tid = threadIdx.x;
    const int i = blockIdx.x * 256 + tid;
    const int v = (i < NN) ? deg[i] : 0;
    s[tid] = v;
    __syncthreads();
    for (int off = 1; off < 256; off <<= 1) {
        int t = (tid >= off) ? s[tid - off] : 0;
        __syncthreads();
        s[tid] += t;
        __syncthreads();
    }
    if (i < NN) rowptr[i] = s[tid] - v;        // block-local exclusive
    if (tid == 255) bsum[blockIdx.x] = s[255];
}

__global__ __launch_bounds__(256) void scan_top_k(int* __restrict__ bsum, int* __restrict__ boff)
{
    __shared__ int s[256];
    const int tid = threadIdx.x;
    const int v = (tid < NSB) ? bsum[tid] : 0;
    s[tid] = v;
    __syncthreads();
    for (int off = 1; off < 256; off <<= 1) {
        int t = (tid >= off) ? s[tid - off] : 0;
        __syncthreads();
        s[tid] += t;
        __syncthreads();
    }
    boff[tid] = s[tid] - v;                    // exclusive
}

__global__ __launch_bounds__(256) void scan_add_k(int* __restrict__ rowptr,
    const int* __restrict__ boff, int* __restrict__ cursor, const int* __restrict__ ecnt)
{
    const int i = blockIdx.x * 256 + threadIdx.x;
    if (i < NN) {
        const int r = rowptr[i] + boff[blockIdx.x];
        rowptr[i] = r;
        cursor[i] = r;
    }
    if (i == 0) rowptr[NN] = *ecnt;
}

// ---------------- fill CSR: edges sorted by recv ----------------
__global__ __launch_bounds__(256) void csr_fill_k(
    const int* __restrict__ cse, const int* __restrict__ cre, const int* __restrict__ ecnt,
    const unsigned short* __restrict__ e8u, int* __restrict__ cursor,
    int* __restrict__ csr_s, int* __restrict__ csr_r, unsigned short* __restrict__ e8c)
{
    const int i = blockIdx.x * 256 + threadIdx.x;
    if (i >= *ecnt) return;
    const int r = cre[i];
    const int pos = atomicAdd(&cursor[r], 1);
    csr_s[pos] = cse[i];
    csr_r[pos] = r;
    *(ushort8*)&e8c[(size_t)pos * 8] = *(const ushort8*)&e8u[(size_t)i * 8];
}

// ---------------- pack ALL weights into MFMA fragment order, one launch ----------------
__device__ __forceinline__ void pack_one(const float* __restrict__ w, unsigned short* __restrict__ out,
                                         int KIN, int NT, int NCOL, int idx)
{
    int i = idx & 7;
    int lane = (idx >> 3) & 63;
    int t = idx >> 9;            // kt*NT + nt
    int nt = t % NT, kt = t / NT;
    int k = kt * 32 + (lane >> 4) * 8 + i;
    int n = nt * 16 + (lane & 15);
    out[idx] = (k < KIN) ? f2b(w[(size_t)k * NCOL + n]) : (unsigned short)0;
}

// segments (256 elems/block):
//  [0,32)    w1s0: m0w1 KIN=19  NT=16 NCOL=256
//  [32,160)  w2s0: m0w2 KIN=256 NT=8  NCOL=128
//  [160,448) w1s1: m1w1 KIN=263 NT=16 NCOL=256
//  [448,576) w2s1: m1w2 KIN=256 NT=8  NCOL=128
//  [576,640) wss : sgw  KIN=128 NT=8  NCOL=128
//  [640,704) wup1: uw1  KIN=128 NT=8  NCOL=128
//  [704,736) wup2: uw2  KIN=128 NT=4  NCOL=64
__global__ __launch_bounds__(256) void pack_all_k(
    const float* __restrict__ m0w1, const float* __restrict__ m0w2,
    const float* __restrict__ m1w1, const float* __restrict__ m1w2,
    const float* __restrict__ sgw,  const float* __restrict__ uw1,
    const float* __restrict__ uw2,
    unsigned short* __restrict__ w1s0, unsigned short* __restrict__ w2s0,
    unsigned short* __restrict__ w1s1, unsigned short* __restrict__ w2s1,
    unsigned short* __restrict__ wss,  unsigned short* __restrict__ wup1,
    unsigned short* __restrict__ wup2)
{
    const int b = blockIdx.x, tid = threadIdx.x;
    if (b < 32)        pack_one(m0w1, w1s0, 19, 16, 256, (b - 0) * 256 + tid);
    else if (b < 160)  pack_one(m0w2, w2s0, 256, 8, 128, (b - 32) * 256 + tid);
    else if (b < 448)  pack_one(m1w1, w1s1, 263, 16, 256, (b - 160) * 256 + tid);
    else if (b < 576)  pack_one(m1w2, w2s1, 256, 8, 128, (b - 448) * 256 + tid);
    else if (b < 640)  pack_one(sgw,  wss, 128, 8, 128, (b - 576) * 256 + tid);
    else if (b < 704)  pack_one(uw1,  wup1, 128, 8, 128, (b - 640) * 256 + tid);
    else               pack_one(uw2,  wup2, 128, 4, 64, (b - 704) * 256 + tid);
}

// ---------------- fp32 -> bf16 bulk convert ----------------
__global__ __launch_bounds__(256) void f2b_k(const float* __restrict__ in,
                                             unsigned short* __restrict__ out, int n8)
{
    int i = blockIdx.x * 256 + threadIdx.x;
    if (i >= n8) return;
    const float4 a = ((const float4*)in)[i * 2];
    const float4 b = ((const float4*)in)[i * 2 + 1];
    ushort8 o;
    o[0] = f2b(a.x); o[1] = f2b(a.y); o[2] = f2b(a.z); o[3] = f2b(a.w);
    o[4] = f2b(b.x); o[5] = f2b(b.y); o[6] = f2b(b.z); o[7] = f2b(b.w);
    ((ushort8*)out)[i] = o;
}

// ---------------- MFMA edge message MLP (operand-swapped D^T = W*X, LDS-staged) ----------------
// HD=128: h rows staged COALESCED into swizzled 32KB LDS tile; s_a/s_t/s_f all union on it.
// HD=6:   tiny separate s_a6 [64][40] staging (5KB) + the 32KB s_t/s_f union tile.
// launch_bounds(256,4): 128-VGPR cap — fits the accumulator set with NO spill.
// (round-6 lesson: (256,5) forced 48 VGPR -> accumulators spilled -> ~530MB scratch HBM, 2x slower.)
template<int HD>
__global__ __launch_bounds__(256, 4) void msg_mfma_k(
    const void* __restrict__ hin,            // HD=6: const float* x; HD=128: const ushort* h1b
    const unsigned short* __restrict__ e8b,  // [NE][8] bf16 edge features (CSR order)
    const int* __restrict__ csr_s, const int* __restrict__ csr_r,
    const int* __restrict__ ecnt,
    const unsigned short* __restrict__ w1s, const float* __restrict__ b1,
    const unsigned short* __restrict__ w2s, const float* __restrict__ b2,
    float* __restrict__ hout)                                              // [NN,128] zeroed
{
    extern __shared__ char smem[];
    char* s_tf = smem;                                                   // 32768 B union tile
    unsigned short (*s_a6)[40] = (unsigned short (*)[40])(smem + 32768); // HD==6 only

    const int Ec = *ecnt;
    const int e0 = blockIdx.x * 64;
    if (e0 >= Ec) return;
    const int tid = threadIdx.x;
    const int wv = tid >> 6, lane = tid & 63, lhi = lane >> 4, llo = lane & 15;
    const short8* w1f = (const short8*)w1s;
    const short8* w2f = (const short8*)w2s;

    // ---- layer 1: D1^T[256 out][64 edge] = W1^T-packed x X^T ----
    f32x4 acc[4][4];                       // [mt(out tile)][nt(edge tile)]
    #pragma unroll
    for (int mt = 0; mt < 4; ++mt) {
        const f32x4 bv = *(const f32x4*)&b1[wv * 64 + mt * 16 + lhi * 4];
        #pragma unroll
        for (int nt = 0; nt < 4; ++nt) acc[mt][nt] = bv;
    }

    if constexpr (HD == 128) {
        // ---- stage: 4 threads/edge, 128B contiguous each -> swizzled LDS row [recv(256B)|send(256B)] ----
        {
            const unsigned short* hb = (const unsigned short*)hin;
            const int eg = tid >> 2, p = tid & 3;
            const int e = e0 + eg;
            const bool ev = e < Ec;
            const unsigned short* src = hb;
            if (ev) {
                const int nid = (p < 2) ? csr_r[e] : csr_s[e];
                src = hb + (size_t)nid * 128 + (p & 1) * 64;
            }
            #pragma unroll
            for (int i = 0; i < 8; ++i) {
                ushort8 v = ushort8(0);
                if (ev) v = *(const ushort8*)(src + i * 8);
                *(ushort8*)(s_tf + swz(eg, p * 128 + i * 16)) = v;
            }
        }
        __syncthreads();
        // ---- K-tiles 0..7 (h parts) from LDS ----
        #pragma unroll
        for (int kt = 0; kt < 8; ++kt) {
            short8 bf[4];
            #pragma unroll
            for (int nt = 0; nt < 4; ++nt)
                bf[nt] = *(const short8*)(s_tf + swz(nt * 16 + llo, kt * 64 + lhi * 16));
            #pragma unroll
            for (int mt = 0; mt < 4; ++mt) {
                const short8 aw = w1f[(kt * 16 + wv * 4 + mt) * 64 + lane];
                #pragma unroll
                for (int nt = 0; nt < 4; ++nt)
                    acc[mt][nt] = __builtin_amdgcn_mfma_f32_16x16x32_bf16(aw, bf[nt], acc[mt][nt], 0, 0, 0);
            }
        }
        // ---- K-tile 8: e-features direct from global (contiguous 256B per 16-lane group) ----
        {
            short8 bf[4];
            #pragma unroll
            for (int nt = 0; nt < 4; ++nt) {
                short8 v = short8(0);
                if (lhi == 0) v = *(const short8*)(e8b + (size_t)(e0 + nt * 16 + llo) * 8);
                bf[nt] = v;
            }
            #pragma unroll
            for (int mt = 0; mt < 4; ++mt) {
                const short8 aw = w1f[(8 * 16 + wv * 4 + mt) * 64 + lane];
                #pragma unroll
                for (int nt = 0; nt < 4; ++nt)
                    acc[mt][nt] = __builtin_amdgcn_mfma_f32_16x16x32_bf16(aw, bf[nt], acc[mt][nt], 0, 0, 0);
            }
        }
    } else {
        // ---- stage tiny s_a6 [64][40] (KIN=19 padded with zeros) ----
        if (tid < 64) {
            const float* xf = (const float*)hin;
            const int e = e0 + tid;
            const bool ev = e < Ec;
            unsigned short u[40];
            #pragma unroll
            for (int c = 0; c < 40; ++c) u[c] = 0;
            if (ev) {
                const int s = csr_s[e], r = csr_r[e];
                const float* xr = xf + (size_t)r * 6;
                const float* xs = xf + (size_t)s * 6;
                #pragma unroll
                for (int c = 0; c < 6; ++c) { u[c] = f2b(xr[c]); u[6 + c] = f2b(xs[c]); }
                #pragma unroll
                for (int c = 0; c < 7; ++c) u[12 + c] = e8b[(size_t)e * 8 + c];
            }
            #pragma unroll
            for (int c = 0; c < 5; ++c)
                *(ushort8*)&s_a6[tid][c * 8] = *(ushort8*)&u[c * 8];
        }
        __syncthreads();
        {
            short8 bf[4];
            #pragma unroll
            for (int nt = 0; nt < 4; ++nt)
                bf[nt] = *(const short8*)&s_a6[nt * 16 + llo][lhi * 8];
            #pragma unroll
            for (int mt = 0; mt < 4; ++mt) {
                const short8 aw = w1f[(wv * 4 + mt) * 64 + lane];
                #pragma unroll
                for (int nt = 0; nt < 4; ++nt)
                    acc[mt][nt] = __builtin_amdgcn_mfma_f32_16x16x32_bf16(aw, bf[nt], acc[mt][nt], 0, 0, 0);
            }
        }
    }
    __syncthreads();                 // all tile reads done before s_t overwrites the region

    // ---- layer-1 epilogue: relu -> bf16, 8B packed writes to swizzled s_t[edge][out] ----
    #pragma unroll
    for (int mt = 0; mt < 4; ++mt)
        #pragma unroll
        for (int nt = 0; nt < 4; ++nt) {
            const int row = nt * 16 + llo;
            const int m0 = wv * 64 + mt * 16 + lhi * 4;
            ushort4 v;
            v.x = f2b(fmaxf(acc[mt][nt][0], 0.f));
            v.y = f2b(fmaxf(acc[mt][nt][1], 0.f));
            v.z = f2b(fmaxf(acc[mt][nt][2], 0.f));
            v.w = f2b(fmaxf(acc[mt][nt][3], 0.f));
            *(ushort4*)(s_tf + swz(row, m0 * 2)) = v;
        }
    __syncthreads();

    // ---- layer 2: D2^T[128 out][64 edge] = W2-packed x T^T ----
    f32x4 acc2[2][4];
    #pragma unroll
    for (int q = 0; q < 2; ++q) {
        const f32x4 bv = *(const f32x4*)&b2[wv * 32 + q * 16 + lhi * 4];
        #pragma unroll
        for (int nt = 0; nt < 4; ++nt) acc2[q][nt] = bv;
    }
    #pragma unroll
    for (int kt = 0; kt < 8; ++kt) {
        short8 bt[4];
        #pragma unroll
        for (int nt = 0; nt < 4; ++nt)
            bt[nt] = *(const short8*)(s_tf + swz(nt * 16 + llo, kt * 64 + lhi * 16));
        #pragma unroll
        for (int q = 0; q < 2; ++q) {
            const short8 aw = w2f[(kt * 8 + wv * 2 + q) * 64 + lane];
            #pragma unroll
            for (int nt = 0; nt < 4; ++nt)
                acc2[q][nt] = __builtin_amdgcn_mfma_f32_16x16x32_bf16(aw, bt[nt], acc2[q][nt], 0, 0, 0);
        }
    }
    __syncthreads();                 // all s_t reads done before f32 overlay writes

    #pragma unroll
    for (int q = 0; q < 2; ++q)
        #pragma unroll
        for (int nt = 0; nt < 4; ++nt) {
            const int row = nt * 16 + llo;
            const int o0 = wv * 32 + q * 16 + lhi * 4;
            float4 v = make_float4(fmaxf(acc2[q][nt][0], 0.f), fmaxf(acc2[q][nt][1], 0.f),
                                   fmaxf(acc2[q][nt][2], 0.f), fmaxf(acc2[q][nt][3], 0.f));
            *(float4*)(s_tf + swz(row, o0 * 4)) = v;
        }
    __syncthreads();

    // ---- run-segmented scatter: edges sorted by recv -> one atomic per run ----
    {
        const int c = tid & 127, hf = tid >> 7;
        int cur = -1; float run = 0.f;
        for (int i = 0; i < 32; ++i) {
            const int row = hf * 32 + i;
            if (e0 + row >= Ec) break;
            const int rv = csr_r[e0 + row];
            const float val = *(const float*)(s_tf + swz(row, c * 4));
            if (rv != cur) {
                if (cur >= 0) unsafeAtomicAdd(&hout[(size_t)cur * 128 + c], run);
                cur = rv; run = 0.f;
            }
            run += val;
        }
        if (cur >= 0) unsafeAtomicAdd(&hout[(size_t)cur * 128 + c], run);
    }
}

// ---------------- node update MLP via MFMA: 128 -> 128 -> 64 ----------------
__global__ __launch_bounds__(256) void upd_mfma_k(
    const float* __restrict__ hin,                                         // [NN,128] fp32
    const unsigned short* __restrict__ w1p, const float* __restrict__ b1,  // packed [4][8][64][8]
    const unsigned short* __restrict__ w2p, const float* __restrict__ b2,  // packed [4][4][64][8]
    float* __restrict__ hout)                                              // [NN,64]
{
    __shared__ unsigned short s_in[64][136];
    __shared__ unsigned short s_t[64][136];
    const int tid = threadIdx.x;
    const int n0 = blockIdx.x * 64;

    { // stage: 4 threads/node, 32 cols each, fp32 -> bf16
        const int ng = tid >> 2, p = tid & 3;
        const int n = n0 + ng;
        if (n < NN) {
            const float* src = hin + (size_t)n * 128 + p * 32;
            unsigned short u[32];
            #pragma unroll
            for (int k = 0; k < 8; ++k) {
                const float4 v = *(const float4*)(src + k * 4);
                u[k*4] = f2b(v.x); u[k*4+1] = f2b(v.y); u[k*4+2] = f2b(v.z); u[k*4+3] = f2b(v.w);
            }
            #pragma unroll
            for (int k = 0; k < 4; ++k)
                *(ushort8*)&s_in[ng][p * 32 + k * 8] = *(ushort8*)&u[k * 8];
        } else {
            #pragma unroll
            for (int k = 0; k < 4; ++k)
                *(ushort8*)&s_in[ng][p * 32 + k * 8] = ushort8(0);
        }
    }
    __syncthreads();

    const int wv = tid >> 6, lane = tid & 63, lhi = lane >> 4, llo = lane & 15;
    const short8* w1f = (const short8*)w1p;
    const short8* w2f = (const short8*)w2p;

    { // layer1: [64,128]x[128,128]; wave wv owns cols wv*32..+31
        f32x4 acc[2][4];
        #pragma unroll
        for (int q = 0; q < 2; ++q) {
            const float bv = b1[(wv * 2 + q) * 16 + llo];
            #pragma unroll
            for (int mt = 0; mt < 4; ++mt) acc[q][mt] = f32x4{bv, bv, bv, bv};
        }
        #pragma unroll
        for (int kt = 0; kt < 4; ++kt) {
            short8 af[4];
            #pragma unroll
            for (int mt = 0; mt < 4; ++mt)
                af[mt] = *(const short8*)&s_in[mt * 16 + llo][kt * 32 + lhi * 8];
            #pragma unroll
            for (int q = 0; q < 2; ++q) {
                const short8 bf = w1f[(kt * 8 + wv * 2 + q) * 64 + lane];
                #pragma unroll
                for (int mt = 0; mt < 4; ++mt)
                    acc[q][mt] = __builtin_amdgcn_mfma_f32_16x16x32_bf16(af[mt], bf, acc[q][mt], 0, 0, 0);
            }
        }
        #pragma unroll
        for (int q = 0; q < 2; ++q)
            #pragma unroll
            for (int mt = 0; mt < 4; ++mt)
                #pragma unroll
                for (int r = 0; r < 4; ++r)
                    s_t[mt * 16 + lhi * 4 + r][(wv * 2 + q) * 16 + llo] =
                        f2b(fmaxf(acc[q][mt][r], 0.f));
    }
    __syncthreads();

    { // layer2: [64,128]x[128,64]; wave wv owns cols wv*16..+15
        f32x4 acc[4];
        const float bv = b2[wv * 16 + llo];
        #pragma unroll
        for (int mt = 0; mt < 4; ++mt) acc[mt] = f32x4{bv, bv, bv, bv};
        #pragma unroll
        for (int kt = 0; kt < 4; ++kt) {
            short8 af[4];
            #pragma unroll
            for (int mt = 0; mt < 4; ++mt)
                af[mt] = *(const short8*)&s_t[mt * 16 + llo][kt * 32 + lhi * 8];
            const short8 bf = w2f[(kt * 4 + wv) * 64 + lane];
            #pragma unroll
            for (int mt = 0; mt < 4; ++mt)
                acc[mt] = __builtin_amdgcn_mfma_f32_16x16x32_bf16(af[mt], bf, acc[mt], 0, 0, 0);
        }
        #pragma unroll
        for (int mt = 0; mt < 4; ++mt)
            #pragma unroll
            for (int r = 0; r < 4; ++r) {
                const int n = n0 + mt * 16 + lhi * 4 + r;
                if (n < NN)
                    hout[(size_t)n * 64 + wv * 16 + llo] = fmaxf(acc[mt][r], 0.f);
            }
    }
}

// ---------------- SAGE: inline CSR gather-mean + MFMA transform + l2norm + pooled reduce ----------------
__global__ __launch_bounds__(256) void sage_node_k(
    const float* __restrict__ hu,                       // [NN,64]
    const int* __restrict__ rowptr, const int* __restrict__ csr_s,
    const int* __restrict__ seg,
    const unsigned short* __restrict__ wss, const float* __restrict__ sb,  // packed [4][8][64][8]
    float* __restrict__ pmax, float* __restrict__ psum, float* __restrict__ npn)
{
    __shared__ unsigned short s_in[64][136];
    __shared__ float s_g[64][130];
    __shared__ float s_inv[64];
    __shared__ int   s_seg[64];
    const int tid = threadIdx.x;
    const int n0 = blockIdx.x * 64;

    { // ---- stage: 4 threads/node, 16 cols each; gather neighbor mean from CSR ----
        const int ng = tid >> 2, p = tid & 3;
        const int n = n0 + ng;
        if (n < NN) {
            if (p == 0) s_seg[ng] = seg[n];
            const float* hr = hu + (size_t)n * 64 + p * 16;
            float a[16];
            #pragma unroll
            for (int k = 0; k < 4; ++k) {
                const float4 v = *(const float4*)(hr + k * 4);
                a[k*4] = v.x; a[k*4+1] = v.y; a[k*4+2] = v.z; a[k*4+3] = v.w;
            }
            float s[16];
            #pragma unroll
            for (int k = 0; k < 16; ++k) s[k] = 0.f;
            const int rb = rowptr[n], re = rowptr[n + 1];
            for (int e = rb; e < re; ++e) {
                const float* hs = hu + (size_t)csr_s[e] * 64 + p * 16;
                #pragma unroll
                for (int k = 0; k < 4; ++k) {
                    const float4 v = *(const float4*)(hs + k * 4);
                    s[k*4] += v.x; s[k*4+1] += v.y; s[k*4+2] += v.z; s[k*4+3] += v.w;
                }
            }
            const float inv = (re > rb) ? 1.f / (float)(re - rb) : 0.f;
            unsigned short uh[16], ua[16];
            #pragma unroll
            for (int k = 0; k < 16; ++k) { uh[k] = f2b(a[k]); ua[k] = f2b(s[k] * inv); }
            *(ushort8*)&s_in[ng][p * 16]          = *(ushort8*)&uh[0];
            *(ushort8*)&s_in[ng][p * 16 + 8]      = *(ushort8*)&uh[8];
            *(ushort8*)&s_in[ng][64 + p * 16]     = *(ushort8*)&ua[0];
            *(ushort8*)&s_in[ng][64 + p * 16 + 8] = *(ushort8*)&ua[8];
        } else {
            if (p == 0) s_seg[ng] = -1;
            *(ushort8*)&s_in[ng][p * 16]          = ushort8(0);
            *(ushort8*)&s_in[ng][p * 16 + 8]      = ushort8(0);
            *(ushort8*)&s_in[ng][64 + p * 16]     = ushort8(0);
            *(ushort8*)&s_in[ng][64 + p * 16 + 8] = ushort8(0);
        }
    }
    __syncthreads();

    const int wv = tid >> 6, lane = tid & 63, lhi = lane >> 4, llo = lane & 15;
    const short8* wf = (const short8*)wss;
    { // ---- [64,128] x [128,128] MFMA; wave wv owns cols wv*32..wv*32+31 ----
        f32x4 acc[2][4];
        #pragma unroll
        for (int q = 0; q < 2; ++q) {
            const float bv = sb[(wv * 2 + q) * 16 + llo];
            #pragma unroll
            for (int mt = 0; mt < 4; ++mt) acc[q][mt] = f32x4{bv, bv, bv, bv};
        }
        #pragma unroll
        for (int kt = 0; kt < 4; ++kt) {
            short8 af[4];
            #pragma unroll
            for (int mt = 0; mt < 4; ++mt)
                af[mt] = *(const short8*)&s_in[mt * 16 + llo][kt * 32 + lhi * 8];
            #pragma unroll
            for (int q = 0; q < 2; ++q) {
                const short8 bf = wf[(kt * 8 + wv * 2 + q) * 64 + lane];
                #pragma unroll
                for (int mt = 0; mt < 4; ++mt)
                    acc[q][mt] = __builtin_amdgcn_mfma_f32_16x16x32_bf16(af[mt], bf, acc[q][mt], 0, 0, 0);
            }
        }
        #pragma unroll
        for (int q = 0; q < 2; ++q)
            #pragma unroll
            for (int mt = 0; mt < 4; ++mt)
                #pragma unroll
                for (int r = 0; r < 4; ++r)
                    s_g[mt * 16 + lhi * 4 + r][(wv * 2 + q) * 16 + llo] = acc[q][mt][r];
    }
    __syncthreads();
    { // ---- l2 norm (pre-relu, fp32): 4 threads/row ----
        const int row = tid >> 2, p = tid & 3;
        float ss = 0.f;
        #pragma unroll
        for (int k = 0; k < 32; ++k) { const float v = s_g[row][p * 32 + k]; ss += v * v; }
        ss += __shfl_xor(ss, 1);
        ss += __shfl_xor(ss, 2);
        if (p == 0) s_inv[row] = rsqrtf(fmaxf(ss, 1e-12f));
    }
    __syncthreads();
    { // ---- run-segmented pooling: seg sorted -> one atomic pair per run per col ----
        const int c = tid & 127, hf = tid >> 7;
        int cur = -1; float rs = 0.f, rm = 0.f;     // g >= 0, so 0 is a valid max identity
        for (int i = 0; i < 32; ++i) {
            const int row = hf * 32 + i;
            if (n0 + row >= NN) break;
            const int sg = s_seg[row];
            const float g = fmaxf(s_g[row][c] * s_inv[row], 0.f);
            if (sg != cur) {
                if (cur >= 0) {
                    unsafeAtomicAdd(&psum[(size_t)cur * 128 + c], rs);
                    atomicMax((unsigned int*)&pmax[(size_t)cur * 128 + c], __float_as_uint(rm));
                }
                cur = sg; rs = 0.f; rm = 0.f;
            }
            rs += g; rm = fmaxf(rm, g);
        }
        if (cur >= 0) {
            unsafeAtomicAdd(&psum[(size_t)cur * 128 + c], rs);
            atomicMax((unsigned int*)&pmax[(size_t)cur * 128 + c], __float_as_uint(rm));
        }
    }
    if (tid == 0 || tid == 128) { // ---- npn: node counts per run ----
        const int hf = tid >> 7;
        int cur = -1; float cnt = 0.f;
        for (int i = 0; i < 32; ++i) {
            const int row = hf * 32 + i;
            if (n0 + row >= NN) break;
            const int sg = s_seg[row];
            if (sg != cur) { if (cur >= 0) unsafeAtomicAdd(&npn[cur], cnt); cur = sg; cnt = 0.f; }
            cnt += 1.f;
        }
        if (cur >= 0) unsafeAtomicAdd(&npn[cur], cnt);
    }
}

// ---------------- decoder + heads ----------------
__global__ __launch_bounds__(256) void dec_heads_k(
    const float* __restrict__ pmax, const float* __restrict__ psum, const float* __restrict__ npn,
    const float* __restrict__ d0w, const float* __restrict__ d0b,
    const float* __restrict__ g0, const float* __restrict__ be0,
    const float* __restrict__ m0, const float* __restrict__ v0,
    const float* __restrict__ d1w, const float* __restrict__ d1b,
    const float* __restrict__ g1, const float* __restrict__ be1,
    const float* __restrict__ m1, const float* __restrict__ v1,
    const float* __restrict__ lw0, const float* __restrict__ lb0,
    const float* __restrict__ lw1, const float* __restrict__ lb1,
    const float* __restrict__ lwo, const float* __restrict__ lbo,
    const float* __restrict__ aw0, const float* __restrict__ ab0,
    const float* __restrict__ aw1, const float* __restrict__ ab1,
    const float* __restrict__ awo, const float* __restrict__ abo,
    const float* __restrict__ sw0, const float* __restrict__ sb0,
    const float* __restrict__ sw1, const float* __restrict__ sb1,
    const float* __restrict__ swo, const float* __restrict__ sbo,
    const float* __restrict__ ascw, const float* __restrict__ ascb,
    float* __restrict__ out)
{
    __shared__ float z0[384];
    __shared__ float z1[1024];
    __shared__ float z2[512];
    __shared__ float ha[192];
    __shared__ float hb[192];
    __shared__ float fin[8];
    const int b = blockIdx.x, tid = threadIdx.x;
    if (tid < 128) {
        const float pm = pmax[(size_t)b * 128 + tid];
        const float ps = psum[(size_t)b * 128 + tid];
        const float nv = fmaxf(npn[b], 1.f);
        z0[tid] = pm; z0[128 + tid] = ps / nv; z0[256 + tid] = ps;
    }
    __syncthreads();
    {
        float acc[4] = { d0b[tid], d0b[tid + 256], d0b[tid + 512], d0b[tid + 768] };
        for (int k = 0; k < 384; ++k) {
            const float zk = z0[k];
            const float* wr = d0w + (size_t)k * 1024 + tid;
            acc[0] += zk * wr[0]; acc[1] += zk * wr[256]; acc[2] += zk * wr[512]; acc[3] += zk * wr[768];
        }
        #pragma unroll
        for (int i = 0; i < 4; ++i) {
            const int j = tid + 256 * i;
            float v = acc[i] > 0.f ? acc[i] : 0.15f * acc[i];
            v = (v - m0[j]) * (1.f / sqrtf(v0[j] + 1e-3f)) * g0[j] + be0[j];
            z1[j] = v;
        }
    }
    __syncthreads();
    {
        float acc[2] = { d1b[tid], d1b[tid + 256] };
        for (int k = 0; k < 1024; ++k) {
            const float zk = z1[k];
            const float* wr = d1w + (size_t)k * 512 + tid;
            acc[0] += zk * wr[0]; acc[1] += zk * wr[256];
        }
        #pragma unroll
        for (int i = 0; i < 2; ++i) {
            const int j = tid + 256 * i;
            float v = acc[i] > 0.f ? acc[i] : 0.15f * acc[i];
            v = (v - m1[j]) * (1.f / sqrtf(v1[j] + 1e-3f)) * g1[j] + be1[j];
            z2[j] = v;
        }
    }
    __syncthreads();
    if (tid < 192) {
        const int hd = tid >> 6, j = tid & 63;
        const float* w0 = hd == 0 ? lw0 : (hd == 1 ? aw0 : sw0);
        const float* b0 = hd == 0 ? lb0 : (hd == 1 ? ab0 : sb0);
        float acc = b0[j];
        for (int k = 0; k < 512; ++k) acc += z2[k] * w0[(size_t)k * 64 + j];
        ha[tid] = acc;
    }
    __syncthreads();
    if (tid < 192) {
        const int hd = tid >> 6, j = tid & 63;
        const float* w1p = hd == 0 ? lw1 : (hd == 1 ? aw1 : sw1);
        const float* b1p = hd == 0 ? lb1 : (hd == 1 ? ab1 : sb1);
        const float* src = &ha[hd * 64];
        float acc = b1p[j];
        for (int k = 0; k < 64; ++k) acc += src[k] * w1p[(size_t)k * 64 + j];
        hb[tid] = acc;
    }
    __syncthreads();
    if (tid < 5) {
        float acc;
        if (tid == 0) { acc = lbo[0]; for (int k = 0; k < 64; ++k) acc += hb[k] * lwo[k]; }
        else if (tid < 3) { const int c = tid - 1; acc = abo[c]; for (int k = 0; k < 64; ++k) acc += hb[64 + k] * awo[k * 2 + c]; }
        else { const int c = tid - 3; acc = sbo[c]; for (int k = 0; k < 64; ++k) acc += hb[128 + k] * swo[k * 2 + c]; }
        fin[tid] = acc;
    }
    __syncthreads();
    if (tid == 0) {
        const float a0 = fin[1], a1 = fin[2];
        const float q0 = a0 * ascw[0] + a1 * ascw[2] + ascb[0];
        const float q1 = a0 * ascw[1] + a1 * ascw[3] + ascb[1];
        const float zen = 1.f / (1.f + expf(-q0));
        const float azi = 1.f / (1.f + expf(-q1));
        const float PI = 3.14159265358979323846f;
        float* o = out + (size_t)b * 5;
        o[0] = fin[0];
        o[1] = zen * PI;
        o[2] = azi * 2.f * PI;
        o[3] = fabsf(fin[3]) + 1e-5f;
        o[4] = fabsf(fin[4]) + 1e-5f;
    }
}

extern "C" void kernel_launch(void* const* d_in, const int* in_sizes, int n_in,
                              void* d_out, int out_size, void* d_ws, size_t ws_size,
                              hipStream_t stream)
{
    const float* x    = (const float*)d_in[0];
    const int* send   = (const int*)d_in[1];
    const int* recv   = (const int*)d_in[2];
    const int* seg    = (const int*)d_in[3];
    const float* m0w1 = (const float*)d_in[4];
    const float* m0b1 = (const float*)d_in[5];
    const float* m0w2 = (const float*)d_in[6];
    const float* m0b2 = (const float*)d_in[7];
    const float* m1w1 = (const float*)d_in[8];
    const float* m1b1 = (const float*)d_in[9];
    const float* m1w2 = (const float*)d_in[10];
    const float* m1b2 = (const float*)d_in[11];
    const float* uw1  = (const float*)d_in[12];
    const float* ub1  = (const float*)d_in[13];
    const float* uw2  = (const float*)d_in[14];
    const float* ub2  = (const float*)d_in[15];
    const float* sgw  = (const float*)d_in[16];
    const float* sgb  = (const float*)d_in[17];
    const float* d0w  = (const float*)d_in[18];
    const float* d0b  = (const float*)d_in[19];
    const float* bn0g = (const float*)d_in[20];
    const float* bn0b = (const float*)d_in[21];
    const float* bn0m = (const float*)d_in[22];
    const float* bn0v = (const float*)d_in[23];
    const float* d1w  = (const float*)d_in[24];
    const float* d1b  = (const float*)d_in[25];
    const float* bn1g = (const float*)d_in[26];
    const float* bn1b = (const float*)d_in[27];
    const float* bn1m = (const float*)d_in[28];
    const float* bn1v = (const float*)d_in[29];
    const float* lw0  = (const float*)d_in[30];
    const float* lb0  = (const float*)d_in[31];
    const float* lw1  = (const float*)d_in[32];
    const float* lb1  = (const float*)d_in[33];
    const float* lwo  = (const float*)d_in[34];
    const float* lbo  = (const float*)d_in[35];
    const float* aw0  = (const float*)d_in[36];
    const float* ab0  = (const float*)d_in[37];
    const float* aw1  = (const float*)d_in[38];
    const float* ab1  = (const float*)d_in[39];
    const float* awo  = (const float*)d_in[40];
    const float* abo  = (const float*)d_in[41];
    const float* sw0  = (const float*)d_in[42];
    const float* sb0  = (const float*)d_in[43];
    const float* sw1  = (const float*)d_in[44];
    const float* sb1  = (const float*)d_in[45];
    const float* swo  = (const float*)d_in[46];
    const float* sbo  = (const float*)d_in[47];
    const float* ascw = (const float*)d_in[48];
    const float* ascb = (const float*)d_in[49];

    char* ws = (char*)d_ws;
    size_t off = 0;
    auto alloc = [&](size_t bytes) { void* p = ws + off; off = (off + bytes + 31) & ~(size_t)31; return p; };
    // ---- single contiguous zero region: h1,h2,pmax,psum,npn,deg,ecnt ----
    float* h1   = (float*)alloc((size_t)NN * 128 * 4);
    float* h2   = (float*)alloc((size_t)NN * 128 * 4);
    float* pmax = (float*)alloc((size_t)NB * 128 * 4);
    float* psum = (float*)alloc((size_t)NB * 128 * 4);
    float* npn  = (float*)alloc((size_t)NB * 4);
    int* deg    = (int*)alloc((size_t)NN * 4);
    int* ecnt   = (int*)alloc(4);
    const size_t zero_bytes = (size_t)((char*)ecnt - (char*)h1) + sizeof(int);
    // ---- non-zeroed scratch ----
    unsigned short* e8u = (unsigned short*)alloc((size_t)NE * 8 * 2);
    unsigned short* e8c = (unsigned short*)alloc((size_t)NE * 8 * 2);
    int* cse    = (int*)alloc((size_t)NE * 4);
    int* cre    = (int*)alloc((size_t)NE * 4);
    int* csr_s  = (int*)alloc((size_t)NE * 4);
    int* csr_r  = (int*)alloc((size_t)NE * 4);
    int* rowptr = (int*)alloc((size_t)(NN + 1) * 4);
    int* cursor = (int*)alloc((size_t)NN * 4);
    int* bsum   = (int*)alloc(256 * 4);
    int* boff   = (int*)alloc(256 * 4);
    unsigned short* h1b  = (unsigned short*)alloc((size_t)NN * 128 * 2);
    unsigned short* w1s0 = (unsigned short*)alloc((size_t)1 * 16 * 512 * 2);
    unsigned short* w2s0 = (unsigned short*)alloc((size_t)8 * 8 * 512 * 2);
    unsigned short* w1s1 = (unsigned short*)alloc((size_t)9 * 16 * 512 * 2);
    unsigned short* w2s1 = (unsigned short*)alloc((size_t)8 * 8 * 512 * 2);
    unsigned short* wss  = (unsigned short*)alloc((size_t)4 * 8 * 512 * 2);
    unsigned short* wup1 = (unsigned short*)alloc((size_t)4 * 8 * 512 * 2);
    unsigned short* wup2 = (unsigned short*)alloc((size_t)4 * 4 * 512 * 2);
    float* hu = h1;                                   // [N,64] (h1 fp32 dead after f2b)

    hipMemsetAsync(h1, 0, zero_bytes, stream);

    pack_all_k<<<736, 256, 0, stream>>>(m0w1, m0w2, m1w1, m1w2, sgw, uw1, uw2,
                                        w1s0, w2s0, w1s1, w2s1, wss, wup1, wup2);

    edge_compact_k<<<(NE + 255) / 256, 256, 0, stream>>>(x, send, recv, e8u, cse, cre, ecnt, deg);
    scan_block_k<<<NSB, 256, 0, stream>>>(deg, rowptr, bsum);
    scan_top_k<<<1, 256, 0, stream>>>(bsum, boff);
    scan_add_k<<<NSB, 256, 0, stream>>>(rowptr, boff, cursor, ecnt);
    csr_fill_k<<<(NE + 255) / 256, 256, 0, stream>>>(cse, cre, ecnt, e8u, cursor, csr_s, csr_r, e8c);

    msg_mfma_k<6><<<NE / 64, 256, 32768 + 5120, stream>>>(
        x, e8c, csr_s, csr_r, ecnt, w1s0, m0b1, w2s0, m0b2, h1);
    f2b_k<<<(NN * 128 / 8 + 255) / 256, 256, 0, stream>>>(h1, h1b, NN * 128 / 8);
    msg_mfma_k<128><<<NE / 64, 256, 32768, stream>>>(
        h1b, e8c, csr_s, csr_r, ecnt, w1s1, m1b1, w2s1, m1b2, h2);
    upd_mfma_k<<<(NN + 63) / 64, 256, 0, stream>>>(h2, wup1, ub1, wup2, ub2, hu);
    sage_node_k<<<(NN + 63) / 64, 256, 0, stream>>>(hu, rowptr, csr_s, seg, wss, sgb, pmax, psum, npn);
    dec_heads_k<<<NB, 256, 0, stream>>>(pmax, psum, npn,
        d0w, d0b, bn0g, bn0b, bn0m, bn0v,
        d1w, d1b, bn1g, bn1b, bn1m, bn1v,
        lw0, lb0, lw1, lb1, lwo, lbo,
        aw0, ab0, aw1, ab1, awo, abo,
        sw0, sb0, sw1, sb1, swo, sbo,
        ascw, ascb, (float*)d_out);
}